// Round 1
// baseline (63.403 us; speedup 1.0000x reference)
//
#include <hip/hip_runtime.h>

// desc[b,f,i,:] = sum_j s(|ri-rj|) * (ri-rj), s = smooth cosine cutoff
// B=4,F=4,N=1024 -> 16 frames, 16.8M pairs. Compute-bound (sqrt+cos per pair).
//
// Layout: 1024 blocks = 16 frames x 64 i-blocks (16 i each).
// Block = 256 threads = 16 i_local x 16 j-chunks (64 j each).
// Frame coords staged in LDS as float4 (16KB). Chunk-rotated j index keeps
// ds_read_b128 conflict-free (4 distinct addrs/wave -> distinct bank quads).

#define NA   1024
#define IPB  16
#define JLEN 64

__global__ __launch_bounds__(256) void desc_kernel(const float* __restrict__ coord,
                                                   float* __restrict__ out) {
    __shared__ float4 s_c[NA];          // padded coords, 16 KB
    __shared__ float  s_red[4][IPB][3]; // per-wave partials

    const int tid     = threadIdx.x;
    const int blk     = blockIdx.x;
    const int frame   = blk >> 6;   // 16 frames
    const int ibk     = blk & 63;   // 64 i-blocks per frame
    const int i_local = tid & 15;
    const int jc      = tid >> 4;   // 16 j-chunks

    const float* gf = coord + frame * (NA * 3);

    // stage frame coords -> padded float4 LDS
    for (int a = tid; a < NA; a += 256) {
        s_c[a] = make_float4(gf[3 * a], gf[3 * a + 1], gf[3 * a + 2], 0.0f);
    }
    __syncthreads();

    const int    i  = ibk * IPB + i_local;
    const float4 ci = s_c[i];
    const float  cx = ci.x, cy = ci.y, cz = ci.z;

    float ax = 0.0f, ay = 0.0f, az = 0.0f;
    const int   jbase = jc * JLEN;
    const float INV11 = 1.0f / 11.0f;        // rev = (r - 0.5)/(2*5.5)
    const float OFF   = -0.5f / 11.0f;

#pragma unroll 8
    for (int t = 0; t < JLEN; ++t) {
        const int    j  = jbase + ((t + jc) & (JLEN - 1)); // rotation: bank-conflict-free
        const float4 cj = s_c[j];
        const float  dx = cx - cj.x;
        const float  dy = cy - cj.y;
        const float  dz = cz - cj.z;
        const float  d2 = fmaf(dx, dx, fmaf(dy, dy, fmaf(dz, dz, 1e-10f)));
        const float  r  = __builtin_amdgcn_sqrtf(d2);
        float rev = fmaf(r, INV11, OFF);
        rev = fminf(fmaxf(rev, 0.0f), 0.5f);  // clamp -> exact piecewise {1, cos, 0}
        const float s = fmaf(0.5f, __builtin_amdgcn_cosf(rev), 0.5f); // cos in revolutions
        ax = fmaf(s, dx, ax);
        ay = fmaf(s, dy, ay);
        az = fmaf(s, dz, az);
    }

    // reduce across the 4 jc values inside each wave (tid bits 4,5)
    ax += __shfl_xor(ax, 16, 64); ax += __shfl_xor(ax, 32, 64);
    ay += __shfl_xor(ay, 16, 64); ay += __shfl_xor(ay, 32, 64);
    az += __shfl_xor(az, 16, 64); az += __shfl_xor(az, 32, 64);

    const int wave = tid >> 6;
    if ((tid & 48) == 0) {
        s_red[wave][i_local][0] = ax;
        s_red[wave][i_local][1] = ay;
        s_red[wave][i_local][2] = az;
    }
    __syncthreads();

    // final reduce across 4 waves; 48 threads write 16 atoms x 3 comps
    if (tid < IPB * 3) {
        const int il   = tid / 3;
        const int comp = tid - il * 3;
        const float v = s_red[0][il][comp] + s_red[1][il][comp] +
                        s_red[2][il][comp] + s_red[3][il][comp];
        out[frame * (NA * 3) + (ibk * IPB + il) * 3 + comp] = v;
    }
}

extern "C" void kernel_launch(void* const* d_in, const int* in_sizes, int n_in,
                              void* d_out, int out_size, void* d_ws, size_t ws_size,
                              hipStream_t stream) {
    const float* coord = (const float*)d_in[0];
    float*       out   = (float*)d_out;
    (void)d_ws; (void)ws_size; (void)n_in; (void)out_size;

    const int frames = in_sizes[0] / (NA * 3);   // B*F = 16
    const int blocks = frames * (NA / IPB);      // 1024

    hipLaunchKernelGGL(desc_kernel, dim3(blocks), dim3(256), 0, stream, coord, out);
}